// Round 14
// baseline (101.605 us; speedup 1.0000x reference)
//
#include <hip/hip_runtime.h>
#include <hip/hip_bf16.h>

#define S_LEN 2048
#define HEADS 16
#define DIM 64
#define QBLK 64          // fallback q-tile
#define KVBLK 64
#define NBH 64           // B*H
#define NTILES 32        // S_LEN / KVBLK

typedef __attribute__((ext_vector_type(8))) short short8;
typedef __attribute__((ext_vector_type(4))) short short4v;
typedef __attribute__((ext_vector_type(4))) float f32x4;
typedef __attribute__((ext_vector_type(2))) unsigned uint2v;

#if __has_builtin(__builtin_amdgcn_exp2f)
#define EXP2(x) __builtin_amdgcn_exp2f(x)
#else
#define EXP2(x) exp2f(x)
#endif

__device__ __forceinline__ short f2bf(float f) {
    __hip_bfloat16 h = __float2bfloat16(f);
    return *reinterpret_cast<const short*>(&h);
}

// packed f32x2 -> bf16x2 (RNE), one instruction
__device__ __forceinline__ unsigned cvtpk(float lo, float hi) {
    unsigned r;
    asm("v_cvt_pk_bf16_f32 %0, %1, %2" : "=v"(r) : "v"(lo), "v"(hi));
    return r;
}

// ------------- prepass: K -> bf16 fragment-major (QK x32 A-layout) --------
// Kg[bh][t][cb][kc][l][16B]; lane l: row(kv_loc)=l&15, k(d)=kc*32+(l>>4)*8+j
__global__ __launch_bounds__(256)
void prep_k_kernel(const float* __restrict__ k_q, char* __restrict__ Kg)
{
    const int u   = blockIdx.x * 256 + threadIdx.x;
    const int l   = u & 63;
    const int kc  = (u >> 6) & 1;
    const int cb  = (u >> 7) & 3;
    const int t   = (u >> 9) & 31;
    const int bh  = u >> 14;
    const int b   = bh >> 4;
    const int h   = bh & 15;

    const int kv = t * KVBLK + cb * 16 + (l & 15);
    const int d0 = kc * 32 + (l >> 4) * 8;

    const float* src = k_q + ((size_t)b * S_LEN + kv) * (HEADS * DIM) + h * DIM + d0;
    float4 a = *reinterpret_cast<const float4*>(src);
    float4 d = *reinterpret_cast<const float4*>(src + 4);
    short8 f;
    f[0]=f2bf(a.x); f[1]=f2bf(a.y); f[2]=f2bf(a.z); f[3]=f2bf(a.w);
    f[4]=f2bf(d.x); f[5]=f2bf(d.y); f[6]=f2bf(d.z); f[7]=f2bf(d.w);
    *reinterpret_cast<short8*>(Kg + (size_t)u * 16) = f;
}

// ------------- prepass: V -> bf16 transposed fragment-major ---------------
// Vg[bh][t][cb][vc][l][16B]; lane l: {d=vc*32+l15, kv=cb*16+(l>>4)*4..+3}(8B)
//                                    {d=vc*32+16+l15, same kv}(8B)
__global__ __launch_bounds__(256)
void prep_v_kernel(const float* __restrict__ v_q, char* __restrict__ Vg)
{
    __shared__ short Vt[64][72];
    const int tid  = threadIdx.x;
    const int tile = blockIdx.x;
    const int bh   = blockIdx.y;
    const int b    = bh >> 4;
    const int h    = bh & 15;
    const int kvbase = tile * KVBLK;

    {
        const int kv = tid >> 2;
        const int d0 = (tid & 3) * 16;
        const float* src = v_q + ((size_t)b * S_LEN + kvbase + kv) * (HEADS * DIM) + h * DIM + d0;
        #pragma unroll
        for (int g = 0; g < 4; ++g) {
            float4 v = *reinterpret_cast<const float4*>(src + g * 4);
            Vt[d0 + g * 4 + 0][kv] = f2bf(v.x);
            Vt[d0 + g * 4 + 1][kv] = f2bf(v.y);
            Vt[d0 + g * 4 + 2][kv] = f2bf(v.z);
            Vt[d0 + g * 4 + 3][kv] = f2bf(v.w);
        }
    }
    __syncthreads();
    char* base = Vg + ((size_t)bh * NTILES + tile) * 8192;
    #pragma unroll
    for (int j = 0; j < 2; ++j) {
        const int unit = tid + j * 256;
        const int l   = unit & 63;
        const int vc  = (unit >> 6) & 1;
        const int cb  = unit >> 7;
        const int l15 = l & 15;
        const int kv0 = cb * 16 + (l >> 4) * 4;
        const int da  = vc * 32 + l15;
        const int db_ = vc * 32 + 16 + l15;
        short4v x = *reinterpret_cast<const short4v*>(&Vt[da][kv0]);
        short4v y = *reinterpret_cast<const short4v*>(&Vt[db_][kv0]);
        short8 f;
        f[0]=x[0]; f[1]=x[1]; f[2]=x[2]; f[3]=x[3];
        f[4]=y[0]; f[5]=y[1]; f[6]=y[2]; f[7]=y[3];
        *reinterpret_cast<short8*>(base + unit * 16) = f;
    }
}

// ------- main attention: 1-wave blocks, 64 q rows/wave, direct loads ------
__global__ __launch_bounds__(64)
void fa_fwd_pre(const float* __restrict__ q_q, const char* __restrict__ Kg,
                const char* __restrict__ Vg, const float* __restrict__ q_scale,
                const float* __restrict__ k_scale, const float* __restrict__ v_scale,
                float* __restrict__ out)
{
    const int l   = threadIdx.x;       // 0..63
    const int l15 = l & 15;
    const int l4  = l >> 4;

    const int L  = blockIdx.x;         // 2048 blocks: L = p*64 + bh (XCD locality)
    const int bh = L & 63;
    const int p  = L >> 6;             // 0..31
    const int c  = 31 - p;             // heavy chunks dispatched first
    const int b  = bh >> 4;
    const int h  = bh & 15;

    const int sstride = HEADS * DIM;
    const size_t bh_off = ((size_t)b * S_LEN * HEADS + h) * DIM;

    const float c2 = q_scale[h] * k_scale[h] * 0.125f * 1.4426950408889634f;
    const float vs = v_scale[h];

    const char* kbase = Kg + (size_t)bh * NTILES * 8192 + l * 16;
    const char* vbase = Vg + (size_t)bh * NTILES * 8192 + l * 16;

    const int qa0 = c * 64;            // 64 q rows: group g = qa0+g*16 .. +15

    // Q fragments (B-operand): col=q, k=d=kc*32+l4*8+j
    short8 qf[4][2];
    #pragma unroll
    for (int g = 0; g < 4; ++g) {
        const float* qp = q_q + bh_off + (size_t)(qa0 + g * 16 + l15) * sstride;
        #pragma unroll
        for (int kc = 0; kc < 2; ++kc) {
            const int d0 = kc * 32 + l4 * 8;
            float4 a = *reinterpret_cast<const float4*>(qp + d0);
            float4 c4 = *reinterpret_cast<const float4*>(qp + d0 + 4);
            short8 f;
            f[0]=f2bf(a.x*c2); f[1]=f2bf(a.y*c2); f[2]=f2bf(a.z*c2); f[3]=f2bf(a.w*c2);
            f[4]=f2bf(c4.x*c2); f[5]=f2bf(c4.y*c2); f[6]=f2bf(c4.z*c2); f[7]=f2bf(c4.w*c2);
            qf[g][kc] = f;
        }
    }

    f32x4 O[4][4];
    #pragma unroll
    for (int g = 0; g < 4; ++g)
        #pragma unroll
        for (int db = 0; db < 4; ++db)
            O[g][db] = (f32x4){0.f, 0.f, 0.f, 0.f};
    float ls[4] = {0.f, 0.f, 0.f, 0.f};

    const int ntw = c + 1;             // causal tiles this chunk needs

    for (int t = 0; t < ntw; ++t) {
        const char* kp = kbase + (size_t)t * 8192;
        const char* vp = vbase + (size_t)t * 8192;
        const int kvbase = t * KVBLK;
        const bool needMask = (t == ntw - 1);   // only last tile crosses diagonal

        #pragma unroll
        for (int cb = 0; cb < 4; ++cb) {
            // ---- K/V fragments straight from L2 (coalesced b128) ----
            short8 kf0 = *reinterpret_cast<const short8*>(kp + cb * 2048);
            short8 kf1 = *reinterpret_cast<const short8*>(kp + cb * 2048 + 1024);
            short8 vv0 = *reinterpret_cast<const short8*>(vp + cb * 2048);
            short8 vv1 = *reinterpret_cast<const short8*>(vp + cb * 2048 + 1024);

            __builtin_amdgcn_s_setprio(1);
            f32x4 acc[4];
            #pragma unroll
            for (int g = 0; g < 4; ++g) {
                f32x4 a = {0.f, 0.f, 0.f, 0.f};
                a = __builtin_amdgcn_mfma_f32_16x16x32_bf16(kf0, qf[g][0], a, 0, 0, 0);
                a = __builtin_amdgcn_mfma_f32_16x16x32_bf16(kf1, qf[g][1], a, 0, 0, 0);
                acc[g] = a;
            }
            __builtin_amdgcn_s_setprio(0);

            const int kvg = kvbase + cb * 16 + l4 * 4;

            short4v pa[4];
            #pragma unroll
            for (int g = 0; g < 4; ++g) {
                float s0 = acc[g][0], s1 = acc[g][1], s2 = acc[g][2], s3 = acc[g][3];
                if (needMask) {
                    const int qv = qa0 + g * 16 + l15;
                    if (kvg + 0 > qv) s0 = -1e30f;
                    if (kvg + 1 > qv) s1 = -1e30f;
                    if (kvg + 2 > qv) s2 = -1e30f;
                    if (kvg + 3 > qv) s3 = -1e30f;
                }
                const float e0 = EXP2(s0), e1 = EXP2(s1);
                const float e2 = EXP2(s2), e3 = EXP2(s3);
                ls[g] += (e0 + e1) + (e2 + e3);
                uint2v u = { cvtpk(e0, e1), cvtpk(e2, e3) };
                pa[g] = *reinterpret_cast<short4v*>(&u);
            }

            short4v vf0 = { vv0[0], vv0[1], vv0[2], vv0[3] };
            short4v vf1 = { vv0[4], vv0[5], vv0[6], vv0[7] };
            short4v vf2 = { vv1[0], vv1[1], vv1[2], vv1[3] };
            short4v vf3 = { vv1[4], vv1[5], vv1[6], vv1[7] };
            __builtin_amdgcn_s_setprio(1);
            #pragma unroll
            for (int g = 0; g < 4; ++g) {
                O[g][0] = __builtin_amdgcn_mfma_f32_16x16x16bf16_1k(vf0, pa[g], O[g][0], 0, 0, 0);
                O[g][1] = __builtin_amdgcn_mfma_f32_16x16x16bf16_1k(vf1, pa[g], O[g][1], 0, 0, 0);
                O[g][2] = __builtin_amdgcn_mfma_f32_16x16x16bf16_1k(vf2, pa[g], O[g][2], 0, 0, 0);
                O[g][3] = __builtin_amdgcn_mfma_f32_16x16x16bf16_1k(vf3, pa[g], O[g][3], 0, 0, 0);
            }
            __builtin_amdgcn_s_setprio(0);
        }
    }

    // epilogue: reduce ls across l4 groups, normalize, store
    #pragma unroll
    for (int g = 0; g < 4; ++g) {
        float t2 = ls[g];
        t2 += __shfl_xor(t2, 16);
        t2 += __shfl_xor(t2, 32);
        const float inv = vs / t2;
        float* op = out + bh_off + (size_t)(qa0 + g * 16 + l15) * sstride;
        #pragma unroll
        for (int db = 0; db < 4; ++db) {
            float4 o;
            o.x = O[g][db][0] * inv; o.y = O[g][db][1] * inv;
            o.z = O[g][db][2] * inv; o.w = O[g][db][3] * inv;
            *reinterpret_cast<float4*>(op + db * 16 + l4 * 4) = o;
        }
    }
}

// ---------------- fallback (round-1 kernel, used if ws too small) ---------
__global__ __launch_bounds__(256)
void fa_fwd_fallback(const float* __restrict__ q_q, const float* __restrict__ k_q,
                     const float* __restrict__ v_q, const float* __restrict__ q_scale,
                     const float* __restrict__ k_scale, const float* __restrict__ v_scale,
                     float* __restrict__ out)
{
    __shared__ char lds[8192 + 8192 + 4 * 16 * 144];
    char* Kl = lds;
    char* Vl = lds + 8192;
    char* Pl = lds + 16384;

    const int tid = threadIdx.x;
    const int w   = tid >> 6;
    const int l   = tid & 63;
    const int l15 = l & 15;
    const int l4  = l >> 4;

    const int qtile = (int)gridDim.x - 1 - (int)blockIdx.x;
    const int bh = blockIdx.y;
    const int b  = bh >> 4;
    const int h  = bh & 15;

    const int qbase = qtile * QBLK;
    const int sstride = HEADS * DIM;
    const size_t bh_off = ((size_t)b * S_LEN * HEADS + h) * DIM;

    const float c2 = q_scale[h] * k_scale[h] * 0.125f * 1.4426950408889634f;
    const float vs = v_scale[h];

    short8 qf[2];
    const int w_qmin = qbase + w * 16;
    {
        const float* qp = q_q + bh_off + (size_t)(w_qmin + l15) * sstride;
        #pragma unroll
        for (int kc = 0; kc < 2; ++kc) {
            const int d0 = kc * 32 + l4 * 8;
            float4 a = *reinterpret_cast<const float4*>(qp + d0);
            float4 c = *reinterpret_cast<const float4*>(qp + d0 + 4);
            short8 f;
            f[0]=f2bf(a.x*c2); f[1]=f2bf(a.y*c2); f[2]=f2bf(a.z*c2); f[3]=f2bf(a.w*c2);
            f[4]=f2bf(c.x*c2); f[5]=f2bf(c.y*c2); f[6]=f2bf(c.z*c2); f[7]=f2bf(c.w*c2);
            qf[kc] = f;
        }
    }

    f32x4 O[4] = {{0.f,0.f,0.f,0.f},{0.f,0.f,0.f,0.f},{0.f,0.f,0.f,0.f},{0.f,0.f,0.f,0.f}};
    float m2[4], lsum[4];
    #pragma unroll
    for (int r = 0; r < 4; ++r) { m2[r] = -1e30f; lsum[r] = 0.f; }

    const int kv_end = qbase + QBLK;

    for (int kvbase = 0; kvbase < kv_end; kvbase += KVBLK) {
        __syncthreads();
        {
            const float* kp = k_q + bh_off + (size_t)kvbase * sstride;
            #pragma unroll
            for (int i = 0; i < 4; ++i) {
                const int f4i = tid + i * 256;
                const int row  = f4i >> 4;
                const int col4 = (f4i & 15) * 4;
                float4 v = *reinterpret_cast<const float4*>(kp + (size_t)row * sstride + col4);
                uint2 pk;
                pk.x = (unsigned)(unsigned short)f2bf(v.x) | ((unsigned)(unsigned short)f2bf(v.y) << 16);
                pk.y = (unsigned)(unsigned short)f2bf(v.z) | ((unsigned)(unsigned short)f2bf(v.w) << 16);
                const int byte = row * 128 + ((col4 * 2) ^ ((row & 7) << 4));
                *reinterpret_cast<uint2*>(&Kl[byte]) = pk;
            }
        }
        {
            const float* vp = v_q + bh_off + (size_t)kvbase * sstride;
            #pragma unroll
            for (int g = 0; g < 2; ++g) {
                const int kv0 = w * 16 + g * 8;
                short8 f;
                #pragma unroll
                for (int j = 0; j < 8; ++j)
                    f[j] = f2bf(vp[(size_t)(kv0 + j) * sstride + l]);
                const int byte = l * 128 + ((kv0 * 2) ^ ((l & 7) << 4));
                *reinterpret_cast<short8*>(&Vl[byte]) = f;
            }
        }
        __syncthreads();

        const bool needMask = (kvbase + KVBLK - 1 > w_qmin);
        f32x4 sc[4];
        #pragma unroll
        for (int cb = 0; cb < 4; ++cb) {
            f32x4 acc = {0.f, 0.f, 0.f, 0.f};
            #pragma unroll
            for (int kc = 0; kc < 2; ++kc) {
                const int row  = cb * 16 + l15;
                const int colb = (kc * 32 + l4 * 8) * 2;
                short8 bf = *reinterpret_cast<const short8*>(
                    &Kl[row * 128 + (colb ^ ((row & 7) << 4))]);
                acc = __builtin_amdgcn_mfma_f32_16x16x32_bf16(qf[kc], bf, acc, 0, 0, 0);
            }
            sc[cb] = acc;
        }
        float p[4][4];
        #pragma unroll
        for (int cb = 0; cb < 4; ++cb) {
            const int kv = kvbase + cb * 16 + l15;
            #pragma unroll
            for (int r = 0; r < 4; ++r) {
                float s = sc[cb][r];
                if (needMask && kv > (w_qmin + l4 * 4 + r)) s = -1e30f;
                p[cb][r] = s;
            }
        }
        char* Pw = Pl + w * (16 * 144);
        #pragma unroll
        for (int r = 0; r < 4; ++r) {
            float t = fmaxf(fmaxf(p[0][r], p[1][r]), fmaxf(p[2][r], p[3][r]));
            t = fmaxf(t, __shfl_xor(t, 1));
            t = fmaxf(t, __shfl_xor(t, 2));
            t = fmaxf(t, __shfl_xor(t, 4));
            t = fmaxf(t, __shfl_xor(t, 8));
            const float mn   = fmaxf(m2[r], t);
            const float corr = exp2f(m2[r] - mn);
            m2[r] = mn;
            lsum[r] *= corr;
            #pragma unroll
            for (int db = 0; db < 4; ++db) O[db][r] *= corr;
            float ps = 0.f;
            #pragma unroll
            for (int cb = 0; cb < 4; ++cb) {
                const float e = exp2f(p[cb][r] - mn);
                p[cb][r] = e;
                ps += e;
            }
            lsum[r] += ps;
            const int prow = l4 * 4 + r;
            #pragma unroll
            for (int cb = 0; cb < 4; ++cb)
                *reinterpret_cast<short*>(&Pw[prow * 144 + (cb * 16 + l15) * 2]) =
                    f2bf(p[cb][r]);
        }
        #pragma unroll
        for (int kc = 0; kc < 2; ++kc) {
            short8 pf = *reinterpret_cast<const short8*>(
                &Pw[l15 * 144 + (kc * 32 + l4 * 8) * 2]);
            #pragma unroll
            for (int db = 0; db < 4; ++db) {
                const int row  = db * 16 + l15;
                const int colb = (kc * 32 + l4 * 8) * 2;
                short8 vf = *reinterpret_cast<const short8*>(
                    &Vl[row * 128 + (colb ^ ((row & 7) << 4))]);
                O[db] = __builtin_amdgcn_mfma_f32_16x16x32_bf16(pf, vf, O[db], 0, 0, 0);
            }
        }
    }

    #pragma unroll
    for (int r = 0; r < 4; ++r) {
        float t = lsum[r];
        t += __shfl_xor(t, 1);
        t += __shfl_xor(t, 2);
        t += __shfl_xor(t, 4);
        t += __shfl_xor(t, 8);
        const float inv = vs / t;
        const int q = w_qmin + l4 * 4 + r;
        float* op = out + bh_off + (size_t)q * sstride;
        #pragma unroll
        for (int db = 0; db < 4; ++db)
            op[db * 16 + l15] = O[db][r] * inv;
    }
}

extern "C" void kernel_launch(void* const* d_in, const int* in_sizes, int n_in,
                              void* d_out, int out_size, void* d_ws, size_t ws_size,
                              hipStream_t stream) {
    const float* q_q     = (const float*)d_in[0];
    const float* k_q     = (const float*)d_in[1];
    const float* v_q     = (const float*)d_in[2];
    const float* q_scale = (const float*)d_in[3];
    const float* k_scale = (const float*)d_in[4];
    const float* v_scale = (const float*)d_in[5];
    float* out = (float*)d_out;

    const size_t kbytes = (size_t)NBH * S_LEN * 128;   // 16.78 MB
    const size_t need   = kbytes * 2;

    if (ws_size >= need) {
        char* Kg = (char*)d_ws;
        char* Vg = Kg + kbytes;
        prep_k_kernel<<<dim3(4096), dim3(256), 0, stream>>>(k_q, Kg);
        prep_v_kernel<<<dim3(NTILES, NBH), dim3(256), 0, stream>>>(v_q, Vg);
        fa_fwd_pre<<<dim3(2048), dim3(64), 0, stream>>>(
            q_q, Kg, Vg, q_scale, k_scale, v_scale, out);
    } else {
        fa_fwd_fallback<<<dim3(NTILES, NBH), dim3(256), 0, stream>>>(
            q_q, k_q, v_q, q_scale, k_scale, v_scale, out);
    }
}

// Round 15
// 100.076 us; speedup vs baseline: 1.0153x; 1.0153x over previous
//
#include <hip/hip_runtime.h>
#include <hip/hip_bf16.h>

#define S_LEN 2048
#define HEADS 16
#define DIM 64
#define QBLK 64          // fallback q-tile
#define KVBLK 64
#define NBH 64           // B*H
#define NTILES 32        // S_LEN / KVBLK

typedef __attribute__((ext_vector_type(8))) short short8;
typedef __attribute__((ext_vector_type(4))) short short4v;
typedef __attribute__((ext_vector_type(4))) float f32x4;
typedef __attribute__((ext_vector_type(2))) unsigned uint2v;

#if __has_builtin(__builtin_amdgcn_exp2f)
#define EXP2(x) __builtin_amdgcn_exp2f(x)
#else
#define EXP2(x) exp2f(x)
#endif

__device__ __forceinline__ short f2bf(float f) {
    __hip_bfloat16 h = __float2bfloat16(f);
    return *reinterpret_cast<const short*>(&h);
}

// packed f32x2 -> bf16x2 (RNE), one instruction
__device__ __forceinline__ unsigned cvtpk(float lo, float hi) {
    unsigned r;
    asm("v_cvt_pk_bf16_f32 %0, %1, %2" : "=v"(r) : "v"(lo), "v"(hi));
    return r;
}

// ------------- prepass: K -> bf16 fragment-major (QK x32 A-layout) --------
// Kg[bh][t][cb][kc][l][16B]; lane l: row(kv_loc)=l&15, k(d)=kc*32+(l>>4)*8+j
__global__ __launch_bounds__(256)
void prep_k_kernel(const float* __restrict__ k_q, char* __restrict__ Kg)
{
    const int u   = blockIdx.x * 256 + threadIdx.x;
    const int l   = u & 63;
    const int kc  = (u >> 6) & 1;
    const int cb  = (u >> 7) & 3;
    const int t   = (u >> 9) & 31;
    const int bh  = u >> 14;
    const int b   = bh >> 4;
    const int h   = bh & 15;

    const int kv = t * KVBLK + cb * 16 + (l & 15);
    const int d0 = kc * 32 + (l >> 4) * 8;

    const float* src = k_q + ((size_t)b * S_LEN + kv) * (HEADS * DIM) + h * DIM + d0;
    float4 a = *reinterpret_cast<const float4*>(src);
    float4 d = *reinterpret_cast<const float4*>(src + 4);
    short8 f;
    f[0]=f2bf(a.x); f[1]=f2bf(a.y); f[2]=f2bf(a.z); f[3]=f2bf(a.w);
    f[4]=f2bf(d.x); f[5]=f2bf(d.y); f[6]=f2bf(d.z); f[7]=f2bf(d.w);
    *reinterpret_cast<short8*>(Kg + (size_t)u * 16) = f;
}

// ------------- prepass: V -> bf16 transposed fragment-major ---------------
// Vg[bh][t][cb][vc][l][16B]; lane l: {d=vc*32+l15, kv=cb*16+(l>>4)*4..+3}(8B)
//                                    {d=vc*32+16+l15, same kv}(8B)
__global__ __launch_bounds__(256)
void prep_v_kernel(const float* __restrict__ v_q, char* __restrict__ Vg)
{
    __shared__ short Vt[64][72];
    const int tid  = threadIdx.x;
    const int tile = blockIdx.x;
    const int bh   = blockIdx.y;
    const int b    = bh >> 4;
    const int h    = bh & 15;
    const int kvbase = tile * KVBLK;

    {
        const int kv = tid >> 2;
        const int d0 = (tid & 3) * 16;
        const float* src = v_q + ((size_t)b * S_LEN + kvbase + kv) * (HEADS * DIM) + h * DIM + d0;
        #pragma unroll
        for (int g = 0; g < 4; ++g) {
            float4 v = *reinterpret_cast<const float4*>(src + g * 4);
            Vt[d0 + g * 4 + 0][kv] = f2bf(v.x);
            Vt[d0 + g * 4 + 1][kv] = f2bf(v.y);
            Vt[d0 + g * 4 + 2][kv] = f2bf(v.z);
            Vt[d0 + g * 4 + 3][kv] = f2bf(v.w);
        }
    }
    __syncthreads();
    char* base = Vg + ((size_t)bh * NTILES + tile) * 8192;
    #pragma unroll
    for (int j = 0; j < 2; ++j) {
        const int unit = tid + j * 256;
        const int l   = unit & 63;
        const int vc  = (unit >> 6) & 1;
        const int cb  = unit >> 7;
        const int l15 = l & 15;
        const int kv0 = cb * 16 + (l >> 4) * 4;
        const int da  = vc * 32 + l15;
        const int db_ = vc * 32 + 16 + l15;
        short4v x = *reinterpret_cast<const short4v*>(&Vt[da][kv0]);
        short4v y = *reinterpret_cast<const short4v*>(&Vt[db_][kv0]);
        short8 f;
        f[0]=x[0]; f[1]=x[1]; f[2]=x[2]; f[3]=x[3];
        f[4]=y[0]; f[5]=y[1]; f[6]=y[2]; f[7]=y[3];
        *reinterpret_cast<short8*>(base + unit * 16) = f;
    }
}

// ------- main attention: 4 independent 64-row waves per block (no LDS) ----
// Block L: bh = L&63, u = L>>6; waves take chunks {u, 15-u, 16+u, 31-u}
// -> per-block work = 66 tile-steps, constant (perfect balance).
__global__ __launch_bounds__(256)
void fa_fwd_pre(const float* __restrict__ q_q, const char* __restrict__ Kg,
                const char* __restrict__ Vg, const float* __restrict__ q_scale,
                const float* __restrict__ k_scale, const float* __restrict__ v_scale,
                float* __restrict__ out)
{
    const int tid = threadIdx.x;
    const int w   = tid >> 6;          // 0..3 (independent wave)
    const int l   = tid & 63;
    const int l15 = l & 15;
    const int l4  = l >> 4;

    const int L  = blockIdx.x;         // 512 blocks
    const int bh = L & 63;
    const int u  = L >> 6;             // 0..7
    const int c  = (w == 0) ? u : (w == 1) ? (15 - u) : (w == 2) ? (16 + u) : (31 - u);
    const int b  = bh >> 4;
    const int h  = bh & 15;

    const int sstride = HEADS * DIM;
    const size_t bh_off = ((size_t)b * S_LEN * HEADS + h) * DIM;

    const float c2 = q_scale[h] * k_scale[h] * 0.125f * 1.4426950408889634f;
    const float vs = v_scale[h];

    const char* kbase = Kg + (size_t)bh * NTILES * 8192 + l * 16;
    const char* vbase = Vg + (size_t)bh * NTILES * 8192 + l * 16;

    const int qa0 = c * 64;            // 64 q rows: group g = qa0+g*16 .. +15

    // Q fragments (B-operand): col=q, k=d=kc*32+l4*8+j
    short8 qf[4][2];
    #pragma unroll
    for (int g = 0; g < 4; ++g) {
        const float* qp = q_q + bh_off + (size_t)(qa0 + g * 16 + l15) * sstride;
        #pragma unroll
        for (int kc = 0; kc < 2; ++kc) {
            const int d0 = kc * 32 + l4 * 8;
            float4 a = *reinterpret_cast<const float4*>(qp + d0);
            float4 c4 = *reinterpret_cast<const float4*>(qp + d0 + 4);
            short8 f;
            f[0]=f2bf(a.x*c2); f[1]=f2bf(a.y*c2); f[2]=f2bf(a.z*c2); f[3]=f2bf(a.w*c2);
            f[4]=f2bf(c4.x*c2); f[5]=f2bf(c4.y*c2); f[6]=f2bf(c4.z*c2); f[7]=f2bf(c4.w*c2);
            qf[g][kc] = f;
        }
    }

    f32x4 O[4][4];
    #pragma unroll
    for (int g = 0; g < 4; ++g)
        #pragma unroll
        for (int db = 0; db < 4; ++db)
            O[g][db] = (f32x4){0.f, 0.f, 0.f, 0.f};
    float ls[4] = {0.f, 0.f, 0.f, 0.f};

    const int ntw = c + 1;             // causal tiles this chunk needs

    for (int t = 0; t < ntw; ++t) {
        const char* kp = kbase + (size_t)t * 8192;
        const char* vp = vbase + (size_t)t * 8192;
        const int kvbase = t * KVBLK;
        const bool needMask = (t == ntw - 1);   // only last tile crosses diagonal

        #pragma unroll
        for (int cb = 0; cb < 4; ++cb) {
            // ---- K/V fragments straight from L2/L3 (coalesced b128) ----
            short8 kf0 = *reinterpret_cast<const short8*>(kp + cb * 2048);
            short8 kf1 = *reinterpret_cast<const short8*>(kp + cb * 2048 + 1024);
            short8 vv0 = *reinterpret_cast<const short8*>(vp + cb * 2048);
            short8 vv1 = *reinterpret_cast<const short8*>(vp + cb * 2048 + 1024);

            __builtin_amdgcn_s_setprio(1);
            f32x4 acc[4];
            #pragma unroll
            for (int g = 0; g < 4; ++g) {
                f32x4 a = {0.f, 0.f, 0.f, 0.f};
                a = __builtin_amdgcn_mfma_f32_16x16x32_bf16(kf0, qf[g][0], a, 0, 0, 0);
                a = __builtin_amdgcn_mfma_f32_16x16x32_bf16(kf1, qf[g][1], a, 0, 0, 0);
                acc[g] = a;
            }
            __builtin_amdgcn_s_setprio(0);

            const int kvg = kvbase + cb * 16 + l4 * 4;

            short4v pa[4];
            #pragma unroll
            for (int g = 0; g < 4; ++g) {
                float s0 = acc[g][0], s1 = acc[g][1], s2 = acc[g][2], s3 = acc[g][3];
                if (needMask) {
                    const int qv = qa0 + g * 16 + l15;
                    if (kvg + 0 > qv) s0 = -1e30f;
                    if (kvg + 1 > qv) s1 = -1e30f;
                    if (kvg + 2 > qv) s2 = -1e30f;
                    if (kvg + 3 > qv) s3 = -1e30f;
                }
                const float e0 = EXP2(s0), e1 = EXP2(s1);
                const float e2 = EXP2(s2), e3 = EXP2(s3);
                ls[g] += (e0 + e1) + (e2 + e3);
                uint2v uu = { cvtpk(e0, e1), cvtpk(e2, e3) };
                pa[g] = *reinterpret_cast<short4v*>(&uu);
            }

            short4v vf0 = { vv0[0], vv0[1], vv0[2], vv0[3] };
            short4v vf1 = { vv0[4], vv0[5], vv0[6], vv0[7] };
            short4v vf2 = { vv1[0], vv1[1], vv1[2], vv1[3] };
            short4v vf3 = { vv1[4], vv1[5], vv1[6], vv1[7] };
            __builtin_amdgcn_s_setprio(1);
            #pragma unroll
            for (int g = 0; g < 4; ++g) {
                O[g][0] = __builtin_amdgcn_mfma_f32_16x16x16bf16_1k(vf0, pa[g], O[g][0], 0, 0, 0);
                O[g][1] = __builtin_amdgcn_mfma_f32_16x16x16bf16_1k(vf1, pa[g], O[g][1], 0, 0, 0);
                O[g][2] = __builtin_amdgcn_mfma_f32_16x16x16bf16_1k(vf2, pa[g], O[g][2], 0, 0, 0);
                O[g][3] = __builtin_amdgcn_mfma_f32_16x16x16bf16_1k(vf3, pa[g], O[g][3], 0, 0, 0);
            }
            __builtin_amdgcn_s_setprio(0);
        }
    }

    // epilogue: reduce ls across l4 groups, normalize, store
    #pragma unroll
    for (int g = 0; g < 4; ++g) {
        float t2 = ls[g];
        t2 += __shfl_xor(t2, 16);
        t2 += __shfl_xor(t2, 32);
        const float inv = vs / t2;
        float* op = out + bh_off + (size_t)(qa0 + g * 16 + l15) * sstride;
        #pragma unroll
        for (int db = 0; db < 4; ++db) {
            float4 o;
            o.x = O[g][db][0] * inv; o.y = O[g][db][1] * inv;
            o.z = O[g][db][2] * inv; o.w = O[g][db][3] * inv;
            *reinterpret_cast<float4*>(op + db * 16 + l4 * 4) = o;
        }
    }
}

// ---------------- fallback (round-1 kernel, used if ws too small) ---------
__global__ __launch_bounds__(256)
void fa_fwd_fallback(const float* __restrict__ q_q, const float* __restrict__ k_q,
                     const float* __restrict__ v_q, const float* __restrict__ q_scale,
                     const float* __restrict__ k_scale, const float* __restrict__ v_scale,
                     float* __restrict__ out)
{
    __shared__ char lds[8192 + 8192 + 4 * 16 * 144];
    char* Kl = lds;
    char* Vl = lds + 8192;
    char* Pl = lds + 16384;

    const int tid = threadIdx.x;
    const int w   = tid >> 6;
    const int l   = tid & 63;
    const int l15 = l & 15;
    const int l4  = l >> 4;

    const int qtile = (int)gridDim.x - 1 - (int)blockIdx.x;
    const int bh = blockIdx.y;
    const int b  = bh >> 4;
    const int h  = bh & 15;

    const int qbase = qtile * QBLK;
    const int sstride = HEADS * DIM;
    const size_t bh_off = ((size_t)b * S_LEN * HEADS + h) * DIM;

    const float c2 = q_scale[h] * k_scale[h] * 0.125f * 1.4426950408889634f;
    const float vs = v_scale[h];

    short8 qf[2];
    const int w_qmin = qbase + w * 16;
    {
        const float* qp = q_q + bh_off + (size_t)(w_qmin + l15) * sstride;
        #pragma unroll
        for (int kc = 0; kc < 2; ++kc) {
            const int d0 = kc * 32 + l4 * 8;
            float4 a = *reinterpret_cast<const float4*>(qp + d0);
            float4 c = *reinterpret_cast<const float4*>(qp + d0 + 4);
            short8 f;
            f[0]=f2bf(a.x*c2); f[1]=f2bf(a.y*c2); f[2]=f2bf(a.z*c2); f[3]=f2bf(a.w*c2);
            f[4]=f2bf(c.x*c2); f[5]=f2bf(c.y*c2); f[6]=f2bf(c.z*c2); f[7]=f2bf(c.w*c2);
            qf[kc] = f;
        }
    }

    f32x4 O[4] = {{0.f,0.f,0.f,0.f},{0.f,0.f,0.f,0.f},{0.f,0.f,0.f,0.f},{0.f,0.f,0.f,0.f}};
    float m2[4], lsum[4];
    #pragma unroll
    for (int r = 0; r < 4; ++r) { m2[r] = -1e30f; lsum[r] = 0.f; }

    const int kv_end = qbase + QBLK;

    for (int kvbase = 0; kvbase < kv_end; kvbase += KVBLK) {
        __syncthreads();
        {
            const float* kp = k_q + bh_off + (size_t)kvbase * sstride;
            #pragma unroll
            for (int i = 0; i < 4; ++i) {
                const int f4i = tid + i * 256;
                const int row  = f4i >> 4;
                const int col4 = (f4i & 15) * 4;
                float4 v = *reinterpret_cast<const float4*>(kp + (size_t)row * sstride + col4);
                uint2 pk;
                pk.x = (unsigned)(unsigned short)f2bf(v.x) | ((unsigned)(unsigned short)f2bf(v.y) << 16);
                pk.y = (unsigned)(unsigned short)f2bf(v.z) | ((unsigned)(unsigned short)f2bf(v.w) << 16);
                const int byte = row * 128 + ((col4 * 2) ^ ((row & 7) << 4));
                *reinterpret_cast<uint2*>(&Kl[byte]) = pk;
            }
        }
        {
            const float* vp = v_q + bh_off + (size_t)kvbase * sstride;
            #pragma unroll
            for (int g = 0; g < 2; ++g) {
                const int kv0 = w * 16 + g * 8;
                short8 f;
                #pragma unroll
                for (int j = 0; j < 8; ++j)
                    f[j] = f2bf(vp[(size_t)(kv0 + j) * sstride + l]);
                const int byte = l * 128 + ((kv0 * 2) ^ ((l & 7) << 4));
                *reinterpret_cast<short8*>(&Vl[byte]) = f;
            }
        }
        __syncthreads();

        const bool needMask = (kvbase + KVBLK - 1 > w_qmin);
        f32x4 sc[4];
        #pragma unroll
        for (int cb = 0; cb < 4; ++cb) {
            f32x4 acc = {0.f, 0.f, 0.f, 0.f};
            #pragma unroll
            for (int kc = 0; kc < 2; ++kc) {
                const int row  = cb * 16 + l15;
                const int colb = (kc * 32 + l4 * 8) * 2;
                short8 bf = *reinterpret_cast<const short8*>(
                    &Kl[row * 128 + (colb ^ ((row & 7) << 4))]);
                acc = __builtin_amdgcn_mfma_f32_16x16x32_bf16(qf[kc], bf, acc, 0, 0, 0);
            }
            sc[cb] = acc;
        }
        float p[4][4];
        #pragma unroll
        for (int cb = 0; cb < 4; ++cb) {
            const int kv = kvbase + cb * 16 + l15;
            #pragma unroll
            for (int r = 0; r < 4; ++r) {
                float s = sc[cb][r];
                if (needMask && kv > (w_qmin + l4 * 4 + r)) s = -1e30f;
                p[cb][r] = s;
            }
        }
        char* Pw = Pl + w * (16 * 144);
        #pragma unroll
        for (int r = 0; r < 4; ++r) {
            float t = fmaxf(fmaxf(p[0][r], p[1][r]), fmaxf(p[2][r], p[3][r]));
            t = fmaxf(t, __shfl_xor(t, 1));
            t = fmaxf(t, __shfl_xor(t, 2));
            t = fmaxf(t, __shfl_xor(t, 4));
            t = fmaxf(t, __shfl_xor(t, 8));
            const float mn   = fmaxf(m2[r], t);
            const float corr = exp2f(m2[r] - mn);
            m2[r] = mn;
            lsum[r] *= corr;
            #pragma unroll
            for (int db = 0; db < 4; ++db) O[db][r] *= corr;
            float ps = 0.f;
            #pragma unroll
            for (int cb = 0; cb < 4; ++cb) {
                const float e = exp2f(p[cb][r] - mn);
                p[cb][r] = e;
                ps += e;
            }
            lsum[r] += ps;
            const int prow = l4 * 4 + r;
            #pragma unroll
            for (int cb = 0; cb < 4; ++cb)
                *reinterpret_cast<short*>(&Pw[prow * 144 + (cb * 16 + l15) * 2]) =
                    f2bf(p[cb][r]);
        }
        #pragma unroll
        for (int kc = 0; kc < 2; ++kc) {
            short8 pf = *reinterpret_cast<const short8*>(
                &Pw[l15 * 144 + (kc * 32 + l4 * 8) * 2]);
            #pragma unroll
            for (int db = 0; db < 4; ++db) {
                const int row  = db * 16 + l15;
                const int colb = (kc * 32 + l4 * 8) * 2;
                short8 vf = *reinterpret_cast<const short8*>(
                    &Vl[row * 128 + (colb ^ ((row & 7) << 4))]);
                O[db] = __builtin_amdgcn_mfma_f32_16x16x32_bf16(pf, vf, O[db], 0, 0, 0);
            }
        }
    }

    #pragma unroll
    for (int r = 0; r < 4; ++r) {
        float t = lsum[r];
        t += __shfl_xor(t, 1);
        t += __shfl_xor(t, 2);
        t += __shfl_xor(t, 4);
        t += __shfl_xor(t, 8);
        const float inv = vs / t;
        const int q = w_qmin + l4 * 4 + r;
        float* op = out + bh_off + (size_t)q * sstride;
        #pragma unroll
        for (int db = 0; db < 4; ++db)
            op[db * 16 + l15] = O[db][r] * inv;
    }
}

extern "C" void kernel_launch(void* const* d_in, const int* in_sizes, int n_in,
                              void* d_out, int out_size, void* d_ws, size_t ws_size,
                              hipStream_t stream) {
    const float* q_q     = (const float*)d_in[0];
    const float* k_q     = (const float*)d_in[1];
    const float* v_q     = (const float*)d_in[2];
    const float* q_scale = (const float*)d_in[3];
    const float* k_scale = (const float*)d_in[4];
    const float* v_scale = (const float*)d_in[5];
    float* out = (float*)d_out;

    const size_t kbytes = (size_t)NBH * S_LEN * 128;   // 16.78 MB
    const size_t need   = kbytes * 2;

    if (ws_size >= need) {
        char* Kg = (char*)d_ws;
        char* Vg = Kg + kbytes;
        prep_k_kernel<<<dim3(4096), dim3(256), 0, stream>>>(k_q, Kg);
        prep_v_kernel<<<dim3(NTILES, NBH), dim3(256), 0, stream>>>(v_q, Vg);
        fa_fwd_pre<<<dim3(512), dim3(256), 0, stream>>>(
            q_q, Kg, Vg, q_scale, k_scale, v_scale, out);
    } else {
        fa_fwd_fallback<<<dim3(NTILES, NBH), dim3(256), 0, stream>>>(
            q_q, k_q, v_q, q_scale, k_scale, v_scale, out);
    }
}

// Round 16
// 77.209 us; speedup vs baseline: 1.3160x; 1.2962x over previous
//
#include <hip/hip_runtime.h>
#include <hip/hip_bf16.h>

#define S_LEN 2048
#define HEADS 16
#define DIM 64
#define QBLK 64          // fallback q-tile
#define KVBLK 64
#define NBH 64           // B*H
#define NTILES 32        // S_LEN / KVBLK

typedef __attribute__((ext_vector_type(8))) short short8;
typedef __attribute__((ext_vector_type(4))) short short4v;
typedef __attribute__((ext_vector_type(4))) float f32x4;
typedef __attribute__((ext_vector_type(2))) unsigned uint2v;

#if __has_builtin(__builtin_amdgcn_exp2f)
#define EXP2(x) __builtin_amdgcn_exp2f(x)
#else
#define EXP2(x) exp2f(x)
#endif

__device__ __forceinline__ short f2bf(float f) {
    __hip_bfloat16 h = __float2bfloat16(f);
    return *reinterpret_cast<const short*>(&h);
}

// packed f32x2 -> bf16x2 (RNE), one instruction
__device__ __forceinline__ unsigned cvtpk(float lo, float hi) {
    unsigned r;
    asm("v_cvt_pk_bf16_f32 %0, %1, %2" : "=v"(r) : "v"(lo), "v"(hi));
    return r;
}

// asm-issued 16B global load: opaque to compiler sinking; caller must
// s_waitcnt vmcnt(0) + sched_barrier(0) before consuming (rule #18).
__device__ __forceinline__ short8 gload16(const char* p) {
    short8 r;
    asm volatile("global_load_dwordx4 %0, %1, off" : "=v"(r) : "v"(p));
    return r;
}

// ------------- prepass: K -> bf16 fragment-major (QK x32 A-layout) --------
// Kg[bh][t][cb][kc][l][16B]; lane l: row(kv_loc)=l&15, k(d)=kc*32+(l>>4)*8+j
__global__ __launch_bounds__(256)
void prep_k_kernel(const float* __restrict__ k_q, char* __restrict__ Kg)
{
    const int u   = blockIdx.x * 256 + threadIdx.x;
    const int l   = u & 63;
    const int kc  = (u >> 6) & 1;
    const int cb  = (u >> 7) & 3;
    const int t   = (u >> 9) & 31;
    const int bh  = u >> 14;
    const int b   = bh >> 4;
    const int h   = bh & 15;

    const int kv = t * KVBLK + cb * 16 + (l & 15);
    const int d0 = kc * 32 + (l >> 4) * 8;

    const float* src = k_q + ((size_t)b * S_LEN + kv) * (HEADS * DIM) + h * DIM + d0;
    float4 a = *reinterpret_cast<const float4*>(src);
    float4 d = *reinterpret_cast<const float4*>(src + 4);
    short8 f;
    f[0]=f2bf(a.x); f[1]=f2bf(a.y); f[2]=f2bf(a.z); f[3]=f2bf(a.w);
    f[4]=f2bf(d.x); f[5]=f2bf(d.y); f[6]=f2bf(d.z); f[7]=f2bf(d.w);
    *reinterpret_cast<short8*>(Kg + (size_t)u * 16) = f;
}

// ------------- prepass: V -> bf16 transposed fragment-major ---------------
// Vg[bh][t][cb][vc][l][16B]; lane l: {d=vc*32+l15, kv=cb*16+(l>>4)*4..+3}(8B)
//                                    {d=vc*32+16+l15, same kv}(8B)
__global__ __launch_bounds__(256)
void prep_v_kernel(const float* __restrict__ v_q, char* __restrict__ Vg)
{
    __shared__ short Vt[64][72];
    const int tid  = threadIdx.x;
    const int tile = blockIdx.x;
    const int bh   = blockIdx.y;
    const int b    = bh >> 4;
    const int h    = bh & 15;
    const int kvbase = tile * KVBLK;

    {
        const int kv = tid >> 2;
        const int d0 = (tid & 3) * 16;
        const float* src = v_q + ((size_t)b * S_LEN + kvbase + kv) * (HEADS * DIM) + h * DIM + d0;
        #pragma unroll
        for (int g = 0; g < 4; ++g) {
            float4 v = *reinterpret_cast<const float4*>(src + g * 4);
            Vt[d0 + g * 4 + 0][kv] = f2bf(v.x);
            Vt[d0 + g * 4 + 1][kv] = f2bf(v.y);
            Vt[d0 + g * 4 + 2][kv] = f2bf(v.z);
            Vt[d0 + g * 4 + 3][kv] = f2bf(v.w);
        }
    }
    __syncthreads();
    char* base = Vg + ((size_t)bh * NTILES + tile) * 8192;
    #pragma unroll
    for (int j = 0; j < 2; ++j) {
        const int unit = tid + j * 256;
        const int l   = unit & 63;
        const int vc  = (unit >> 6) & 1;
        const int cb  = unit >> 7;
        const int l15 = l & 15;
        const int kv0 = cb * 16 + (l >> 4) * 4;
        const int da  = vc * 32 + l15;
        const int db_ = vc * 32 + 16 + l15;
        short4v x = *reinterpret_cast<const short4v*>(&Vt[da][kv0]);
        short4v y = *reinterpret_cast<const short4v*>(&Vt[db_][kv0]);
        short8 f;
        f[0]=x[0]; f[1]=x[1]; f[2]=x[2]; f[3]=x[3];
        f[4]=y[0]; f[5]=y[1]; f[6]=y[2]; f[7]=y[3];
        *reinterpret_cast<short8*>(base + unit * 16) = f;
    }
}

// ------- main attention: 1-wave blocks, 32 q rows, batch-issued loads -----
__global__ __launch_bounds__(64)
void fa_fwd_pre(const float* __restrict__ q_q, const char* __restrict__ Kg,
                const char* __restrict__ Vg, const float* __restrict__ q_scale,
                const float* __restrict__ k_scale, const float* __restrict__ v_scale,
                float* __restrict__ out)
{
    const int l   = threadIdx.x;       // 0..63
    const int l15 = l & 15;
    const int l4  = l >> 4;

    const int L  = blockIdx.x;         // 4096 blocks: L = p*64 + bh (XCD locality)
    const int bh = L & 63;
    const int p  = L >> 6;             // 0..63
    const int chunk = 63 - p;          // heavy chunks dispatched first
    const int b  = bh >> 4;
    const int h  = bh & 15;

    const int sstride = HEADS * DIM;
    const size_t bh_off = ((size_t)b * S_LEN * HEADS + h) * DIM;

    const float c2 = q_scale[h] * k_scale[h] * 0.125f * 1.4426950408889634f;
    const float vs = v_scale[h];

    const char* kbase = Kg + (size_t)bh * NTILES * 8192 + l * 16;
    const char* vbase = Vg + (size_t)bh * NTILES * 8192 + l * 16;

    const int qa0 = chunk * 32;
    const int qva = qa0 + l15;
    const int qvb = qva + 16;

    // Q fragments (B-operand): col=q, k=d=kc*32+l4*8+j
    short8 qaf0, qaf1, qbf0, qbf1;
    {
        const float* qp = q_q + bh_off + (size_t)qva * sstride;
        const float* qq = q_q + bh_off + (size_t)qvb * sstride;
        #pragma unroll
        for (int kc = 0; kc < 2; ++kc) {
            const int d0 = kc * 32 + l4 * 8;
            float4 a = *reinterpret_cast<const float4*>(qp + d0);
            float4 c4 = *reinterpret_cast<const float4*>(qp + d0 + 4);
            short8 f;
            f[0]=f2bf(a.x*c2); f[1]=f2bf(a.y*c2); f[2]=f2bf(a.z*c2); f[3]=f2bf(a.w*c2);
            f[4]=f2bf(c4.x*c2); f[5]=f2bf(c4.y*c2); f[6]=f2bf(c4.z*c2); f[7]=f2bf(c4.w*c2);
            if (kc == 0) qaf0 = f; else qaf1 = f;
            float4 a2 = *reinterpret_cast<const float4*>(qq + d0);
            float4 c2v = *reinterpret_cast<const float4*>(qq + d0 + 4);
            short8 g;
            g[0]=f2bf(a2.x*c2); g[1]=f2bf(a2.y*c2); g[2]=f2bf(a2.z*c2); g[3]=f2bf(a2.w*c2);
            g[4]=f2bf(c2v.x*c2); g[5]=f2bf(c2v.y*c2); g[6]=f2bf(c2v.z*c2); g[7]=f2bf(c2v.w*c2);
            if (kc == 0) qbf0 = g; else qbf1 = g;
        }
    }

    f32x4 Oa[4] = {{0.f,0.f,0.f,0.f},{0.f,0.f,0.f,0.f},{0.f,0.f,0.f,0.f},{0.f,0.f,0.f,0.f}};
    f32x4 Ob[4] = {{0.f,0.f,0.f,0.f},{0.f,0.f,0.f,0.f},{0.f,0.f,0.f,0.f},{0.f,0.f,0.f,0.f}};
    float lsa = 0.f, lsb = 0.f;

    const int ntw = ((qa0 + 31) >> 6) + 1;     // causal tiles this chunk needs

    for (int t = 0; t < ntw; ++t) {
        const char* kp = kbase + (size_t)t * 8192;
        const char* vp = vbase + (size_t)t * 8192;
        const int kvbase = t * KVBLK;
        const bool mA = (kvbase + KVBLK - 1 > qa0);
        const bool mB = (kvbase + KVBLK - 1 > qa0 + 16);

        // ---- batch-issue ALL 16 tile loads (latencies overlap) ----
        short8 K[8], V[8];
        #pragma unroll
        for (int i = 0; i < 4; ++i) {
            K[2*i]   = gload16(kp + i * 2048);
            K[2*i+1] = gload16(kp + i * 2048 + 1024);
            V[2*i]   = gload16(vp + i * 2048);
            V[2*i+1] = gload16(vp + i * 2048 + 1024);
        }
        asm volatile("s_waitcnt vmcnt(0)" ::: "memory");
        __builtin_amdgcn_sched_barrier(0);

        #pragma unroll
        for (int cb = 0; cb < 4; ++cb) {
            __builtin_amdgcn_s_setprio(1);
            f32x4 aa = {0.f, 0.f, 0.f, 0.f};
            aa = __builtin_amdgcn_mfma_f32_16x16x32_bf16(K[cb*2],   qaf0, aa, 0, 0, 0);
            aa = __builtin_amdgcn_mfma_f32_16x16x32_bf16(K[cb*2+1], qaf1, aa, 0, 0, 0);
            f32x4 ab = {0.f, 0.f, 0.f, 0.f};
            ab = __builtin_amdgcn_mfma_f32_16x16x32_bf16(K[cb*2],   qbf0, ab, 0, 0, 0);
            ab = __builtin_amdgcn_mfma_f32_16x16x32_bf16(K[cb*2+1], qbf1, ab, 0, 0, 0);
            __builtin_amdgcn_s_setprio(0);

            const int kvg = kvbase + cb * 16 + l4 * 4;

            float sa0 = aa[0], sa1 = aa[1], sa2 = aa[2], sa3 = aa[3];
            if (mA) {
                if (kvg + 0 > qva) sa0 = -1e30f;
                if (kvg + 1 > qva) sa1 = -1e30f;
                if (kvg + 2 > qva) sa2 = -1e30f;
                if (kvg + 3 > qva) sa3 = -1e30f;
            }
            const float ea0 = EXP2(sa0), ea1 = EXP2(sa1);
            const float ea2 = EXP2(sa2), ea3 = EXP2(sa3);
            lsa += (ea0 + ea1) + (ea2 + ea3);
            uint2v ua = { cvtpk(ea0, ea1), cvtpk(ea2, ea3) };
            short4v pa = *reinterpret_cast<short4v*>(&ua);

            float sb0 = ab[0], sb1 = ab[1], sb2 = ab[2], sb3 = ab[3];
            if (mB) {
                if (kvg + 0 > qvb) sb0 = -1e30f;
                if (kvg + 1 > qvb) sb1 = -1e30f;
                if (kvg + 2 > qvb) sb2 = -1e30f;
                if (kvg + 3 > qvb) sb3 = -1e30f;
            }
            const float eb0 = EXP2(sb0), eb1 = EXP2(sb1);
            const float eb2 = EXP2(sb2), eb3 = EXP2(sb3);
            lsb += (eb0 + eb1) + (eb2 + eb3);
            uint2v ub = { cvtpk(eb0, eb1), cvtpk(eb2, eb3) };
            short4v pb = *reinterpret_cast<short4v*>(&ub);

            short4v vf0 = { V[cb*2][0], V[cb*2][1], V[cb*2][2], V[cb*2][3] };
            short4v vf1 = { V[cb*2][4], V[cb*2][5], V[cb*2][6], V[cb*2][7] };
            short4v vf2 = { V[cb*2+1][0], V[cb*2+1][1], V[cb*2+1][2], V[cb*2+1][3] };
            short4v vf3 = { V[cb*2+1][4], V[cb*2+1][5], V[cb*2+1][6], V[cb*2+1][7] };
            __builtin_amdgcn_s_setprio(1);
            Oa[0] = __builtin_amdgcn_mfma_f32_16x16x16bf16_1k(vf0, pa, Oa[0], 0, 0, 0);
            Oa[1] = __builtin_amdgcn_mfma_f32_16x16x16bf16_1k(vf1, pa, Oa[1], 0, 0, 0);
            Oa[2] = __builtin_amdgcn_mfma_f32_16x16x16bf16_1k(vf2, pa, Oa[2], 0, 0, 0);
            Oa[3] = __builtin_amdgcn_mfma_f32_16x16x16bf16_1k(vf3, pa, Oa[3], 0, 0, 0);
            Ob[0] = __builtin_amdgcn_mfma_f32_16x16x16bf16_1k(vf0, pb, Ob[0], 0, 0, 0);
            Ob[1] = __builtin_amdgcn_mfma_f32_16x16x16bf16_1k(vf1, pb, Ob[1], 0, 0, 0);
            Ob[2] = __builtin_amdgcn_mfma_f32_16x16x16bf16_1k(vf2, pb, Ob[2], 0, 0, 0);
            Ob[3] = __builtin_amdgcn_mfma_f32_16x16x16bf16_1k(vf3, pb, Ob[3], 0, 0, 0);
            __builtin_amdgcn_s_setprio(0);
        }
    }

    // epilogue: reduce lsum across l4 groups, normalize, store
    lsa += __shfl_xor(lsa, 16);
    lsa += __shfl_xor(lsa, 32);
    lsb += __shfl_xor(lsb, 16);
    lsb += __shfl_xor(lsb, 32);
    const float inva = vs / lsa;
    const float invb = vs / lsb;
    float* opa = out + bh_off + (size_t)qva * sstride;
    float* opb = out + bh_off + (size_t)qvb * sstride;
    #pragma unroll
    for (int db = 0; db < 4; ++db) {
        float4 o;
        o.x = Oa[db][0] * inva; o.y = Oa[db][1] * inva;
        o.z = Oa[db][2] * inva; o.w = Oa[db][3] * inva;
        *reinterpret_cast<float4*>(opa + db * 16 + l4 * 4) = o;
        float4 q;
        q.x = Ob[db][0] * invb; q.y = Ob[db][1] * invb;
        q.z = Ob[db][2] * invb; q.w = Ob[db][3] * invb;
        *reinterpret_cast<float4*>(opb + db * 16 + l4 * 4) = q;
    }
}

// ---------------- fallback (round-1 kernel, used if ws too small) ---------
__global__ __launch_bounds__(256)
void fa_fwd_fallback(const float* __restrict__ q_q, const float* __restrict__ k_q,
                     const float* __restrict__ v_q, const float* __restrict__ q_scale,
                     const float* __restrict__ k_scale, const float* __restrict__ v_scale,
                     float* __restrict__ out)
{
    __shared__ char lds[8192 + 8192 + 4 * 16 * 144];
    char* Kl = lds;
    char* Vl = lds + 8192;
    char* Pl = lds + 16384;

    const int tid = threadIdx.x;
    const int w   = tid >> 6;
    const int l   = tid & 63;
    const int l15 = l & 15;
    const int l4  = l >> 4;

    const int qtile = (int)gridDim.x - 1 - (int)blockIdx.x;
    const int bh = blockIdx.y;
    const int b  = bh >> 4;
    const int h  = bh & 15;

    const int qbase = qtile * QBLK;
    const int sstride = HEADS * DIM;
    const size_t bh_off = ((size_t)b * S_LEN * HEADS + h) * DIM;

    const float c2 = q_scale[h] * k_scale[h] * 0.125f * 1.4426950408889634f;
    const float vs = v_scale[h];

    short8 qf[2];
    const int w_qmin = qbase + w * 16;
    {
        const float* qp = q_q + bh_off + (size_t)(w_qmin + l15) * sstride;
        #pragma unroll
        for (int kc = 0; kc < 2; ++kc) {
            const int d0 = kc * 32 + l4 * 8;
            float4 a = *reinterpret_cast<const float4*>(qp + d0);
            float4 c = *reinterpret_cast<const float4*>(qp + d0 + 4);
            short8 f;
            f[0]=f2bf(a.x*c2); f[1]=f2bf(a.y*c2); f[2]=f2bf(a.z*c2); f[3]=f2bf(a.w*c2);
            f[4]=f2bf(c.x*c2); f[5]=f2bf(c.y*c2); f[6]=f2bf(c.z*c2); f[7]=f2bf(c.w*c2);
            qf[kc] = f;
        }
    }

    f32x4 O[4] = {{0.f,0.f,0.f,0.f},{0.f,0.f,0.f,0.f},{0.f,0.f,0.f,0.f},{0.f,0.f,0.f,0.f}};
    float m2[4], lsum[4];
    #pragma unroll
    for (int r = 0; r < 4; ++r) { m2[r] = -1e30f; lsum[r] = 0.f; }

    const int kv_end = qbase + QBLK;

    for (int kvbase = 0; kvbase < kv_end; kvbase += KVBLK) {
        __syncthreads();
        {
            const float* kp = k_q + bh_off + (size_t)kvbase * sstride;
            #pragma unroll
            for (int i = 0; i < 4; ++i) {
                const int f4i = tid + i * 256;
                const int row  = f4i >> 4;
                const int col4 = (f4i & 15) * 4;
                float4 v = *reinterpret_cast<const float4*>(kp + (size_t)row * sstride + col4);
                uint2 pk;
                pk.x = (unsigned)(unsigned short)f2bf(v.x) | ((unsigned)(unsigned short)f2bf(v.y) << 16);
                pk.y = (unsigned)(unsigned short)f2bf(v.z) | ((unsigned)(unsigned short)f2bf(v.w) << 16);
                const int byte = row * 128 + ((col4 * 2) ^ ((row & 7) << 4));
                *reinterpret_cast<uint2*>(&Kl[byte]) = pk;
            }
        }
        {
            const float* vp = v_q + bh_off + (size_t)kvbase * sstride;
            #pragma unroll
            for (int g = 0; g < 2; ++g) {
                const int kv0 = w * 16 + g * 8;
                short8 f;
                #pragma unroll
                for (int j = 0; j < 8; ++j)
                    f[j] = f2bf(vp[(size_t)(kv0 + j) * sstride + l]);
                const int byte = l * 128 + ((kv0 * 2) ^ ((l & 7) << 4));
                *reinterpret_cast<short8*>(&Vl[byte]) = f;
            }
        }
        __syncthreads();

        const bool needMask = (kvbase + KVBLK - 1 > w_qmin);
        f32x4 sc[4];
        #pragma unroll
        for (int cb = 0; cb < 4; ++cb) {
            f32x4 acc = {0.f, 0.f, 0.f, 0.f};
            #pragma unroll
            for (int kc = 0; kc < 2; ++kc) {
                const int row  = cb * 16 + l15;
                const int colb = (kc * 32 + l4 * 8) * 2;
                short8 bf = *reinterpret_cast<const short8*>(
                    &Kl[row * 128 + (colb ^ ((row & 7) << 4))]);
                acc = __builtin_amdgcn_mfma_f32_16x16x32_bf16(qf[kc], bf, acc, 0, 0, 0);
            }
            sc[cb] = acc;
        }
        float p[4][4];
        #pragma unroll
        for (int cb = 0; cb < 4; ++cb) {
            const int kv = kvbase + cb * 16 + l15;
            #pragma unroll
            for (int r = 0; r < 4; ++r) {
                float s = sc[cb][r];
                if (needMask && kv > (w_qmin + l4 * 4 + r)) s = -1e30f;
                p[cb][r] = s;
            }
        }
        char* Pw = Pl + w * (16 * 144);
        #pragma unroll
        for (int r = 0; r < 4; ++r) {
            float t = fmaxf(fmaxf(p[0][r], p[1][r]), fmaxf(p[2][r], p[3][r]));
            t = fmaxf(t, __shfl_xor(t, 1));
            t = fmaxf(t, __shfl_xor(t, 2));
            t = fmaxf(t, __shfl_xor(t, 4));
            t = fmaxf(t, __shfl_xor(t, 8));
            const float mn   = fmaxf(m2[r], t);
            const float corr = exp2f(m2[r] - mn);
            m2[r] = mn;
            lsum[r] *= corr;
            #pragma unroll
            for (int db = 0; db < 4; ++db) O[db][r] *= corr;
            float ps = 0.f;
            #pragma unroll
            for (int cb = 0; cb < 4; ++cb) {
                const float e = exp2f(p[cb][r] - mn);
                p[cb][r] = e;
                ps += e;
            }
            lsum[r] += ps;
            const int prow = l4 * 4 + r;
            #pragma unroll
            for (int cb = 0; cb < 4; ++cb)
                *reinterpret_cast<short*>(&Pw[prow * 144 + (cb * 16 + l15) * 2]) =
                    f2bf(p[cb][r]);
        }
        #pragma unroll
        for (int kc = 0; kc < 2; ++kc) {
            short8 pf = *reinterpret_cast<const short8*>(
                &Pw[l15 * 144 + (kc * 32 + l4 * 8) * 2]);
            #pragma unroll
            for (int db = 0; db < 4; ++db) {
                const int row  = db * 16 + l15;
                const int colb = (kc * 32 + l4 * 8) * 2;
                short8 vf = *reinterpret_cast<const short8*>(
                    &Vl[row * 128 + (colb ^ ((row & 7) << 4))]);
                O[db] = __builtin_amdgcn_mfma_f32_16x16x32_bf16(pf, vf, O[db], 0, 0, 0);
            }
        }
    }

    #pragma unroll
    for (int r = 0; r < 4; ++r) {
        float t = lsum[r];
        t += __shfl_xor(t, 1);
        t += __shfl_xor(t, 2);
        t += __shfl_xor(t, 4);
        t += __shfl_xor(t, 8);
        const float inv = vs / t;
        const int q = w_qmin + l4 * 4 + r;
        float* op = out + bh_off + (size_t)q * sstride;
        #pragma unroll
        for (int db = 0; db < 4; ++db)
            op[db * 16 + l15] = O[db][r] * inv;
    }
}

extern "C" void kernel_launch(void* const* d_in, const int* in_sizes, int n_in,
                              void* d_out, int out_size, void* d_ws, size_t ws_size,
                              hipStream_t stream) {
    const float* q_q     = (const float*)d_in[0];
    const float* k_q     = (const float*)d_in[1];
    const float* v_q     = (const float*)d_in[2];
    const float* q_scale = (const float*)d_in[3];
    const float* k_scale = (const float*)d_in[4];
    const float* v_scale = (const float*)d_in[5];
    float* out = (float*)d_out;

    const size_t kbytes = (size_t)NBH * S_LEN * 128;   // 16.78 MB
    const size_t need   = kbytes * 2;

    if (ws_size >= need) {
        char* Kg = (char*)d_ws;
        char* Vg = Kg + kbytes;
        prep_k_kernel<<<dim3(4096), dim3(256), 0, stream>>>(k_q, Kg);
        prep_v_kernel<<<dim3(NTILES, NBH), dim3(256), 0, stream>>>(v_q, Vg);
        fa_fwd_pre<<<dim3(4096), dim3(64), 0, stream>>>(
            q_q, Kg, Vg, q_scale, k_scale, v_scale, out);
    } else {
        fa_fwd_fallback<<<dim3(NTILES, NBH), dim3(256), 0, stream>>>(
            q_q, k_q, v_q, q_scale, k_scale, v_scale, out);
    }
}